// Round 7
// baseline (283.701 us; speedup 1.0000x reference)
//
#include <hip/hip_runtime.h>

#define L2E 1.4426950408889634f
#define LN2D 0.6931471805599453

// ---- async global->LDS DMA (16B per lane: lds_base + lane*16) ----
__device__ __forceinline__ void async_copy16(const float* g, float* l) {
    __builtin_amdgcn_global_load_lds(
        (const __attribute__((address_space(1))) void*)g,
        (__attribute__((address_space(3))) void*)l, 16, 0, 0);
}
// gfx9 s_waitcnt imm: vmcnt[3:0] | expcnt[6:4] | lgkmcnt[11:8] | vmcnt_hi[15:14]
__device__ __forceinline__ void wait_vm0() { __builtin_amdgcn_s_waitcnt(0x0F70); }
__device__ __forceinline__ void wait_vm4() { __builtin_amdgcn_s_waitcnt(0x0F74); }

// f64 lane shifts via 2x 32-bit DPP; bound_ctrl=1 -> 0.0 fill. Pure VALU.
__device__ __forceinline__ double dpp_sr1_f64(double x) {  // lane l <- lane l-1 (lane0 -> 0)
    const int lo = __builtin_amdgcn_update_dpp(0, __double2loint(x), 0x138, 0xF, 0xF, true);
    const int hi = __builtin_amdgcn_update_dpp(0, __double2hiint(x), 0x138, 0xF, 0xF, true);
    return __hiloint2double(hi, lo);
}
__device__ __forceinline__ double dpp_sl1_f64(double x) {  // lane l <- lane l+1 (lane63 -> 0)
    const int lo = __builtin_amdgcn_update_dpp(0, __double2loint(x), 0x130, 0xF, 0xF, true);
    const int hi = __builtin_amdgcn_update_dpp(0, __double2hiint(x), 0x130, 0xF, 0xF, true);
    return __hiloint2double(hi, lo);
}
// wave-wide int max broadcast (off critical path; only positions the f64 window)
__device__ __forceinline__ int wave_imax(int v) {
    int t;
#define DM(ctrl) t = __builtin_amdgcn_update_dpp(v, v, (ctrl), 0xF, 0xF, false); v = (v > t) ? v : t
    DM(0x111); DM(0x112); DM(0x114); DM(0x118);
    DM(0x142); DM(0x143);
#undef DM
    return __builtin_amdgcn_readlane(v, 63);
}

// producer: 4 staged rows (row[k*256 + cls]) -> softmax -> gathered chunk into slot:
//   slot[    4*lane + k] = p(k, tgA)   slot[256 + 4*lane + k] = p(k, tgB)   slot[512+k] = p(k, 0)
__device__ __forceinline__ void produce_chunk(const float* __restrict__ row,
                                              float* __restrict__ slot,
                                              int lane, int tA, int tB) {
    float mk[4], rk[4];
#pragma unroll
    for (int k = 0; k < 4; ++k) {
        const float4 v = *reinterpret_cast<const float4*>(&row[k * 256 + 4 * lane]);
        float m = fmaxf(fmaxf(v.x, v.y), fmaxf(v.z, v.w));
#pragma unroll
        for (int off = 32; off; off >>= 1) m = fmaxf(m, __shfl_xor(m, off, 64));
        float s = exp2f((v.x - m) * L2E) + exp2f((v.y - m) * L2E) +
                  exp2f((v.z - m) * L2E) + exp2f((v.w - m) * L2E);
#pragma unroll
        for (int off = 32; off; off >>= 1) s += __shfl_xor(s, off, 64);
        mk[k] = m; rk[k] = 1.0f / s;
    }
    float4 gA, gB;
    gA.x = exp2f((row[0 * 256 + tA] - mk[0]) * L2E) * rk[0];
    gA.y = exp2f((row[1 * 256 + tA] - mk[1]) * L2E) * rk[1];
    gA.z = exp2f((row[2 * 256 + tA] - mk[2]) * L2E) * rk[2];
    gA.w = exp2f((row[3 * 256 + tA] - mk[3]) * L2E) * rk[3];
    gB.x = exp2f((row[0 * 256 + tB] - mk[0]) * L2E) * rk[0];
    gB.y = exp2f((row[1 * 256 + tB] - mk[1]) * L2E) * rk[1];
    gB.z = exp2f((row[2 * 256 + tB] - mk[2]) * L2E) * rk[2];
    gB.w = exp2f((row[3 * 256 + tB] - mk[3]) * L2E) * rk[3];
    *reinterpret_cast<float4*>(&slot[4 * lane]) = gA;
    *reinterpret_cast<float4*>(&slot[256 + 4 * lane]) = gB;
    if (lane == 0) {
        float4 bb;
        bb.x = exp2f((row[0 * 256] - mk[0]) * L2E) * rk[0];
        bb.y = exp2f((row[1 * 256] - mk[1]) * L2E) * rk[1];
        bb.z = exp2f((row[2 * 256] - mk[2]) * L2E) * rk[2];
        bb.w = exp2f((row[3 * 256] - mk[3]) * L2E) * rk[3];
        *reinterpret_cast<float4*>(&slot[512]) = bb;
    }
}

// ---------------- Fused kernel: 2 blocks per n (h=0: alpha t=0..511; h=1: beta t=1023..511) --
// 4 waves: wave0 = f64 chain consumer; waves 1-3 = softmax/gather producers (DMA-staged).
// 6-slot LDS chunk ring, 3 chunks/round, barrier per round, 43 rounds = 128 chunks/half.
__global__ __launch_bounds__(256) void ctc_fused_kernel(
        const float* __restrict__ preds, const int* __restrict__ targets,
        double* __restrict__ Aws, double* __restrict__ Bws, int* __restrict__ meta) {
    constexpr int T = 1024, L = 128, NCH = 128;
    __shared__ float sSlot[6][520];          // per chunk: A[256] B[256] blank[4]
    __shared__ float sRowBuf[3][2][4 * 256]; // producer-private staging (double-buffered)

    const int n = blockIdx.x >> 1;
    const int h = blockIdx.x & 1;
    const int wv = threadIdx.x >> 6;
    const int lane = threadIdx.x & 63;

    const int* __restrict__ tg = targets + (size_t)n * L;
    const int tA = tg[2 * lane + 0];
    const int tB = tg[2 * lane + 1];
    const float* __restrict__ Pn = preds + (size_t)n * T * 256;

    int tPrev = __shfl_up(tB, 1, 64);
    if (lane == 0) tPrev = 0;
    const int skipAi = (tA != 0 && tA != tPrev) ? 1 : 0;
    const bool skipA = skipAi != 0;
    const bool skipB = (tB != 0) && (tB != tA);
    const double mBd = skipB ? 1.0 : 0.0;
    const double mA1d = (double)__shfl_down(skipAi, 1, 64);
    int cnt = (tA != 0) + (tB != 0);
#pragma unroll
    for (int off = 32; off; off >>= 1) cnt += __shfl_xor(cnt, off, 64);
    const int tl = cnt;
    int i1 = 2 * tl;     if (i1 > 256) i1 = 256;
    int i0 = 2 * tl - 1; if (i0 < 0) i0 += 257;  // JAX negative-index wrap

    // chain state (alpha or beta depending on h)
    double X0 = 0.0, X1 = 0.0, X2 = 0.0, X3 = 0.0, X4 = 0.0;
    if (h == 1) {  // beta init at t = T-1: indicator of final states
        const int s0 = 4 * lane;
        X0 = (s0 == i1 || s0 == i0) ? 1.0 : 0.0;
        X1 = (s0 + 1 == i1 || s0 + 1 == i0) ? 1.0 : 0.0;
        X2 = (s0 + 2 == i1 || s0 + 2 == i0) ? 1.0 : 0.0;
        X3 = (s0 + 3 == i1 || s0 + 3 == i0) ? 1.0 : 0.0;
        X4 = (lane == 63 && (i1 == 256 || i0 == 256)) ? 1.0 : 0.0;
    }
    double sc = 1.0;
    int e_apply = 0, K = 0;

#define ASTEP(PBf, PAf, PB2f) do {                                              \
        const double PB = (double)(PBf), PA = (double)(PAf), PB2 = (double)(PB2f); \
        const double p3 = dpp_sr1_f64(X3);                                      \
        const double u0 = X0 + p3;                                              \
        const double u1 = X1 + X0 + (skipA ? p3 : 0.0);                         \
        const double u2 = X2 + X1;                                              \
        const double u3 = X3 + X2 + (skipB ? X1 : 0.0);                         \
        const double u4 = X4 + X3;                                              \
        X0 = u0 * PB; X1 = u1 * PA; X2 = u2 * PB; X3 = u3 * PB2; X4 = u4 * PB;  \
    } while (0)

#define BSTEP(PBf, PAf, PB2f) do {                                              \
        const double pb_ = (double)(PBf);                                       \
        const double g0 = pb_ * X0;                                             \
        const double g1 = (double)(PAf) * X1;                                   \
        const double g2 = pb_ * X2;                                             \
        const double g3 = (double)(PB2f) * X3;                                  \
        const double g4 = pb_ * X4;                                             \
        double G4 = dpp_sl1_f64(g0);                                            \
        G4 = (lane == 63) ? g4 : G4;                                            \
        const double G5 = dpp_sl1_f64(g1);                                      \
        X0 = g0 + g1;                                                           \
        X1 = fma(mBd, g3, g1 + g2);                                             \
        X2 = g2 + g3;                                                           \
        X3 = fma(mA1d, G5, g3 + G4);                                            \
        X4 = g4;                                                                \
    } while (0)

#define RESCALE() do {                                                          \
        X0 *= sc; X1 *= sc; X2 *= sc; X3 *= sc; X4 *= sc; K += e_apply;         \
        const double m_ = fmax(fmax(fmax(X0, X1), fmax(X2, X3)), X4);           \
        int e_ = ((__double2hiint(m_) >> 20) & 0x7FF) - 1023;                   \
        e_ = wave_imax(e_);                                                     \
        e_ = e_ < -960 ? -960 : (e_ > 960 ? 960 : e_);                          \
        e_apply = e_; sc = __hiloint2double((1023 - e_) << 20, 0);              \
    } while (0)

    wait_vm0();  // drain target loads so producer vmcnt accounting is exact

    // ---- pre-phase: producers stage+produce chunks 0..2 and prefetch chunks 3..5 ----
    if (wv > 0) {
        const int pw = wv - 1;
        const int gc0 = h ? 255 - pw : pw;
#pragma unroll
        for (int k = 0; k < 4; ++k)
            async_copy16(Pn + (size_t)(4 * gc0 + k) * 256 + 4 * lane, &sRowBuf[pw][0][k * 256]);
        wait_vm0();
        produce_chunk(&sRowBuf[pw][0][0], &sSlot[pw][0], lane, tA, tB);
        const int gc1 = h ? 255 - (pw + 3) : (pw + 3);
#pragma unroll
        for (int k = 0; k < 4; ++k)
            async_copy16(Pn + (size_t)(4 * gc1 + k) * 256 + 4 * lane, &sRowBuf[pw][1][k * 256]);
    }
    __syncthreads();

    // ---- main rounds: producers fill round r+1's slots, consumer eats round r's ----
    for (int r = 0; r < 43; ++r) {
        if (wv > 0) {
            const int pw = wv - 1;
            const int cp = 3 * (r + 1) + pw;   // chunk processed this round (buf (r+1)&1)
            const int cn = cp + 3;             // chunk DMA'd this round    (buf r&1)
            if (cn < NCH) {
                const int gcn = h ? 255 - cn : cn;
                float* dst = &sRowBuf[pw][r & 1][0];
#pragma unroll
                for (int k = 0; k < 4; ++k)
                    async_copy16(Pn + (size_t)(4 * gcn + k) * 256 + 4 * lane, dst + k * 256);
            }
            if (cp < NCH) {
                if (cn < NCH) wait_vm4(); else wait_vm0();
                const int slot = pw + (((r + 1) & 1) ? 3 : 0);
                produce_chunk(&sRowBuf[pw][(r + 1) & 1][0], &sSlot[slot][0], lane, tA, tB);
            }
        } else {
            const int sb = (r & 1) ? 3 : 0;
            // j = 0 (c = 3r, always < 128)
            {
                const float4 fA = *reinterpret_cast<const float4*>(&sSlot[sb][4 * lane]);
                const float4 fB = *reinterpret_cast<const float4*>(&sSlot[sb][256 + 4 * lane]);
                const float4 fb = *reinterpret_cast<const float4*>(&sSlot[sb][512]);
                if (h == 0) {
                    if (r == 0) {
                        X0 = lane ? 0.0 : (double)fb.x;
                        X1 = lane ? 0.0 : (double)fA.x;
                        X2 = 0.0; X3 = 0.0; X4 = 0.0;
                    } else ASTEP(fb.x, fA.x, fB.x);
                    ASTEP(fb.y, fA.y, fB.y); ASTEP(fb.z, fA.z, fB.z); ASTEP(fb.w, fA.w, fB.w);
                } else {
                    BSTEP(fb.w, fA.w, fB.w); BSTEP(fb.z, fA.z, fB.z);
                    BSTEP(fb.y, fA.y, fB.y); BSTEP(fb.x, fA.x, fB.x);
                }
            }
            // j = 1 (c = 3r+1, always < 128)
            {
                const float4 fA = *reinterpret_cast<const float4*>(&sSlot[sb + 1][4 * lane]);
                const float4 fB = *reinterpret_cast<const float4*>(&sSlot[sb + 1][256 + 4 * lane]);
                const float4 fb = *reinterpret_cast<const float4*>(&sSlot[sb + 1][512]);
                if (h == 0) {
                    ASTEP(fb.x, fA.x, fB.x); ASTEP(fb.y, fA.y, fB.y);
                    ASTEP(fb.z, fA.z, fB.z); ASTEP(fb.w, fA.w, fB.w);
                } else {
                    BSTEP(fb.w, fA.w, fB.w); BSTEP(fb.z, fA.z, fB.z);
                    BSTEP(fb.y, fA.y, fB.y); BSTEP(fb.x, fA.x, fB.x);
                }
            }
            // j = 2 (c = 3r+2, < 128 except the last round)
            if (3 * r + 2 < NCH) {
                const float4 fA = *reinterpret_cast<const float4*>(&sSlot[sb + 2][4 * lane]);
                const float4 fB = *reinterpret_cast<const float4*>(&sSlot[sb + 2][256 + 4 * lane]);
                const float4 fb = *reinterpret_cast<const float4*>(&sSlot[sb + 2][512]);
                if (h == 0) {
                    ASTEP(fb.x, fA.x, fB.x); ASTEP(fb.y, fA.y, fB.y);
                    ASTEP(fb.z, fA.z, fB.z); ASTEP(fb.w, fA.w, fB.w);
                } else {
                    BSTEP(fb.w, fA.w, fB.w); BSTEP(fb.z, fA.z, fB.z);
                    BSTEP(fb.y, fA.y, fB.y); BSTEP(fb.x, fA.x, fB.x);
                }
            }
            RESCALE();
        }
        __syncthreads();
    }
#undef RESCALE
#undef BSTEP
#undef ASTEP

    if (wv == 0) {
        X0 *= sc; X1 *= sc; X2 *= sc; X3 *= sc; X4 *= sc; K += e_apply;
        double* __restrict__ W = (h ? Bws : Aws) + (size_t)n * 260;
        double4 st; st.x = X0; st.y = X1; st.z = X2; st.w = X3;
        *reinterpret_cast<double4*>(&W[4 * lane]) = st;
        if (lane == 63) W[256] = X4;
        if (lane == 0) {
            if (h == 0) { meta[4 * n + 0] = K; meta[4 * n + 2] = tl; }
            else          meta[4 * n + 1] = K;
        }
    }
}

// ---------------- Combine: P(n) = sum_s alpha_511(s)*beta_511(s); then batch mean ----------
__global__ __launch_bounds__(256) void combine_kernel(const double* __restrict__ Aws,
                                                      const double* __restrict__ Bws,
                                                      const int* __restrict__ meta,
                                                      float* __restrict__ out, int N) {
    __shared__ double sPart[4];
    const int wv = threadIdx.x >> 6, lane = threadIdx.x & 63;
    double acc = 0.0;
    for (int n = wv; n < N; n += 4) {
        const double* A = Aws + (size_t)n * 260;
        const double* B = Bws + (size_t)n * 260;
        const double4 a = *reinterpret_cast<const double4*>(&A[4 * lane]);
        const double4 b = *reinterpret_cast<const double4*>(&B[4 * lane]);
        double S = a.x * b.x + a.y * b.y + a.z * b.z + a.w * b.w;
        if (lane == 63) S += A[256] * B[256];
#pragma unroll
        for (int off = 32; off; off >>= 1) S += __shfl_xor(S, off, 64);
        const int Ksum = meta[4 * n] + meta[4 * n + 1];
        const int tl = meta[4 * n + 2];
        const double loss = (S > 0.0) ? -(log2(S) + (double)Ksum) * LN2D : 0.0;
        acc += loss / (double)(tl > 0 ? tl : 1);
    }
    if (lane == 0) sPart[wv] = acc;
    __syncthreads();
    if (threadIdx.x == 0)
        out[0] = (float)((sPart[0] + sPart[1] + sPart[2] + sPart[3]) / (double)N);
}

extern "C" void kernel_launch(void* const* d_in, const int* in_sizes, int n_in,
                              void* d_out, int out_size, void* d_ws, size_t ws_size,
                              hipStream_t stream) {
    const float* preds = (const float*)d_in[0];
    const int* targets = (const int*)d_in[1];
    const int N = in_sizes[1] / 128;  // 128

    // ws: Aws [N*260 dbl] | Bws [N*260 dbl] | meta [N*4 int]   (~534 KB)
    double* Aws = (double*)d_ws;
    double* Bws = Aws + (size_t)N * 260;
    int* meta = (int*)(Bws + (size_t)N * 260);
    float* out = (float*)d_out;

    ctc_fused_kernel<<<2 * N, 256, 0, stream>>>(preds, targets, Aws, Bws, meta);
    combine_kernel<<<1, 256, 0, stream>>>(Aws, Bws, meta, out, N);
}